// Round 12
// baseline (151.371 us; speedup 1.0000x reference)
//
#include <hip/hip_runtime.h>
#include <hip/hip_bf16.h>

#define BB 2
#define PP 128
#define CC 8
#define EE 1024
#define HH 16
#define KVHH 4
#define DD 64
#define TT 1024
#define EKVV 256

typedef unsigned short u16;
typedef unsigned int u32;
typedef __attribute__((ext_vector_type(8))) short bf16x8;
typedef __attribute__((ext_vector_type(4))) float f32x4;

__device__ __forceinline__ float b2f(u16 u) {
    u32 x = ((u32)u) << 16;
    return __uint_as_float(x);
}
__device__ __forceinline__ u16 f2b(float f) {
    u32 x = __float_as_uint(f);
    u32 r = (x + 0x7FFFu + ((x >> 16) & 1u)) >> 16;
    return (u16)r;
}

// DPP 16-lane reductions (VALU-only; replaces ds_swizzle shfl chains).
template <int CTRL>
__device__ __forceinline__ float dpp_mv(float v) {
    return __int_as_float(__builtin_amdgcn_update_dpp(
        __float_as_int(v), __float_as_int(v), CTRL, 0xF, 0xF, true));
}
__device__ __forceinline__ float red_max16(float v) {
    v = fmaxf(v, dpp_mv<0xB1>(v));   // quad_perm xor1
    v = fmaxf(v, dpp_mv<0x4E>(v));   // quad_perm xor2
    v = fmaxf(v, dpp_mv<0x141>(v));  // row_half_mirror
    v = fmaxf(v, dpp_mv<0x140>(v));  // row_mirror
    return v;
}
__device__ __forceinline__ float red_sum16(float v) {
    v += dpp_mv<0xB1>(v);
    v += dpp_mv<0x4E>(v);
    v += dpp_mv<0x141>(v);
    v += dpp_mv<0x140>(v);
    return v;
}

// async global->LDS 16B (wave-uniform LDS base + lane*16 layout required)
#define GLL16(gp, lp)                                                          \
    __builtin_amdgcn_global_load_lds(                                          \
        (__attribute__((address_space(1))) void*)(gp),                         \
        (__attribute__((address_space(3))) void*)(lp), 16, 0, 0)

// ---------------------------------------------------------------------------
// k_prep: one-time conversions + the two tiny fp32 projections (fused).
//   blocks [0,192):     pos/chan projections, split-K=16 slices (K=64 each)
//   blocks [192,1216):  hidden f32 -> bf16 (hb)
//   blocks [1216,2240): Wq    -> btq rows [0,1024)    (transposed bf16)
//   blocks [2240,2752): Wkv   -> btq rows [1024,1536) (transposed bf16)
//   blocks [2752,3776): Wproj -> btp                  (transposed bf16)
// ---------------------------------------------------------------------------
__global__ __launch_bounds__(256) void k_prep(const float* __restrict__ hidden,
                                              const float* __restrict__ Wq,
                                              const float* __restrict__ Wkv,
                                              const float* __restrict__ Wproj,
                                              const float* __restrict__ pos,
                                              const float* __restrict__ chan,
                                              const float* __restrict__ Wpos,
                                              const float* __restrict__ Wchan,
                                              u16* __restrict__ hb,
                                              u16* __restrict__ btq,
                                              u16* __restrict__ btp,
                                              float* __restrict__ tkb,
                                              float* __restrict__ ckb) {
    __shared__ __align__(16) char sm[8704];
    int bid = blockIdx.x;
    int tid = threadIdx.x;

    if (bid < 192) {
        // tiny fp32 GEMM, K-slice (64) per block, direct store (no atomics)
        int tile = bid >> 4, kh = bid & 15;
        float (*As)[68] = (float (*)[68])sm;
        float (*Bs)[68] = (float (*)[68])(sm + 4352);
        const float* A; const float* B; float* C; int M, m0, n0;
        if (tile < 8) { A = pos;  B = Wpos;  C = tkb + kh * 32768; M = 128; m0 = (tile >> 2) * 64; n0 = (tile & 3) * 64; }
        else          { A = chan; B = Wchan; C = ckb + kh * 2048;  M = 8;   m0 = 0;               n0 = (tile - 8) * 64; }
        int tx = tid & 15, ty = tid >> 4;
        float acc[4][4];
#pragma unroll
        for (int r = 0; r < 4; r++)
#pragma unroll
            for (int c = 0; c < 4; c++) acc[r][c] = 0.f;
        int am = tid >> 2, ak = (tid & 3) << 2;
        int bk = tid >> 4, bn = (tid & 15) << 2;
        for (int k0 = kh * 64; k0 < kh * 64 + 64; k0 += 16) {
            int row = m0 + am;
            float4 av;
            if (row < M) av = *reinterpret_cast<const float4*>(A + (size_t)row * 1024 + k0 + ak);
            else av = make_float4(0.f, 0.f, 0.f, 0.f);
            As[ak + 0][am] = av.x;
            As[ak + 1][am] = av.y;
            As[ak + 2][am] = av.z;
            As[ak + 3][am] = av.w;
            float4 bv = *reinterpret_cast<const float4*>(B + (size_t)(k0 + bk) * 256 + n0 + bn);
            Bs[bk][bn + 0] = bv.x;
            Bs[bk][bn + 1] = bv.y;
            Bs[bk][bn + 2] = bv.z;
            Bs[bk][bn + 3] = bv.w;
            __syncthreads();
#pragma unroll
            for (int kk = 0; kk < 16; kk++) {
                float4 a4 = *reinterpret_cast<const float4*>(&As[kk][ty << 2]);
                float4 b4 = *reinterpret_cast<const float4*>(&Bs[kk][tx << 2]);
                acc[0][0] += a4.x * b4.x; acc[0][1] += a4.x * b4.y; acc[0][2] += a4.x * b4.z; acc[0][3] += a4.x * b4.w;
                acc[1][0] += a4.y * b4.x; acc[1][1] += a4.y * b4.y; acc[1][2] += a4.y * b4.z; acc[1][3] += a4.y * b4.w;
                acc[2][0] += a4.z * b4.x; acc[2][1] += a4.z * b4.y; acc[2][2] += a4.z * b4.z; acc[2][3] += a4.z * b4.w;
                acc[3][0] += a4.w * b4.x; acc[3][1] += a4.w * b4.y; acc[3][2] += a4.w * b4.z; acc[3][3] += a4.w * b4.w;
            }
            __syncthreads();
        }
#pragma unroll
        for (int r = 0; r < 4; r++) {
            int row = m0 + (ty << 2) + r;
            if (row < M) {
#pragma unroll
                for (int c = 0; c < 4; c++) {
                    int col = n0 + (tx << 2) + c;
                    C[(size_t)row * 256 + col] = acc[r][c];
                }
            }
        }
        return;
    }
    bid -= 192;
    if (bid < 1024) {
        int base = (bid * 256 + tid) * 8;
        float4 a0 = *(const float4*)(hidden + base);
        float4 a1 = *(const float4*)(hidden + base + 4);
        u16 o[8] = {f2b(a0.x), f2b(a0.y), f2b(a0.z), f2b(a0.w),
                    f2b(a1.x), f2b(a1.y), f2b(a1.z), f2b(a1.w)};
        *(uint4*)(hb + base) = *(uint4*)o;
        return;
    }
    bid -= 1024;
    const float* W;
    u16* out;
    int N, tk, tn;
    if (bid < 1024) {
        W = Wq; out = btq; N = 1024; tk = bid >> 5; tn = bid & 31;
    } else if (bid < 1536) {
        int b2 = bid - 1024;
        W = Wkv; out = btq + 1024 * 1024; N = 512; tk = b2 >> 4; tn = b2 & 15;
    } else {
        int b2 = bid - 1536;
        W = Wproj; out = btp; N = 1024; tk = b2 >> 5; tn = b2 & 31;
    }
    float (*ts)[33] = (float (*)[33])sm;
    int r = tid >> 3, c4 = (tid & 7) << 2;
    float4 v = *(const float4*)(W + (size_t)(tk * 32 + r) * N + tn * 32 + c4);
    ts[r][c4 + 0] = v.x;
    ts[r][c4 + 1] = v.y;
    ts[r][c4 + 2] = v.z;
    ts[r][c4 + 3] = v.w;
    __syncthreads();
    u16 o[4] = {f2b(ts[c4 + 0][r]), f2b(ts[c4 + 1][r]),
                f2b(ts[c4 + 2][r]), f2b(ts[c4 + 3][r])};
    *(ushort4*)(out + (size_t)(tn * 32 + r) * 1024 + tk * 32 + c4) = *(ushort4*)o;
}

// ---------------------------------------------------------------------------
// mgemm_qkv3: 64x64-tile bf16 GEMM, BK=64 dbuf, XOR-swizzled LDS (unchanged).
// ---------------------------------------------------------------------------
__global__ __launch_bounds__(256) void mgemm_qkv3(const u16* __restrict__ Ab,
                                                  const u16* __restrict__ BT,
                                                  u16* __restrict__ qout,
                                                  u16* __restrict__ kvout,
                                                  u16* __restrict__ vtb,
                                                  const float* __restrict__ tkb,
                                                  const float* __restrict__ ckb,
                                                  u16* __restrict__ tkr,
                                                  float* __restrict__ ckr) {
    __shared__ __align__(16) u16 As[2][64 * 64];
    __shared__ __align__(16) u16 Bs[2][64 * 64];
    int tid = threadIdx.x;
    int ntile = blockIdx.x;

    if (ntile == 24) {
        int y = blockIdx.y;
        if (y >= 16) return;
        // tk reduction: rows [y*8, y*8+8), 256 units of 8 cols each
        int p = y * 8 + (tid >> 5), col = (tid & 31) << 3;
        float s0 = 0.f, s1 = 0.f, s2 = 0.f, s3 = 0.f,
              s4 = 0.f, s5 = 0.f, s6 = 0.f, s7 = 0.f;
#pragma unroll
        for (int sl = 0; sl < 16; sl++) {
            const float* tp = tkb + sl * 32768 + p * 256 + col;
            float4 a0 = *(const float4*)(tp);
            float4 a1 = *(const float4*)(tp + 4);
            s0 += a0.x; s1 += a0.y; s2 += a0.z; s3 += a0.w;
            s4 += a1.x; s5 += a1.y; s6 += a1.z; s7 += a1.w;
        }
        u16 o[8] = {f2b(s0), f2b(s1), f2b(s2), f2b(s3),
                    f2b(s4), f2b(s5), f2b(s6), f2b(s7)};
        int kvh = col >> 6, d = col & 63;
        *(uint4*)(tkr + kvh * 8192 + p * 64 + d) = *(uint4*)o;
        if (y == 0) {
            // ck reduction: 8 c-rows x 256 cols
            int c = tid >> 5, cc = (tid & 31) << 3;
            float t[8];
#pragma unroll
            for (int j = 0; j < 8; j++) t[j] = 0.f;
#pragma unroll
            for (int sl = 0; sl < 16; sl++) {
                const float* cp = ckb + sl * 2048 + c * 256 + cc;
                float4 a0 = *(const float4*)(cp);
                float4 a1 = *(const float4*)(cp + 4);
                t[0] += a0.x; t[1] += a0.y; t[2] += a0.z; t[3] += a0.w;
                t[4] += a1.x; t[5] += a1.y; t[6] += a1.z; t[7] += a1.w;
            }
            int kvh2 = cc >> 6, d2 = cc & 63;
            float* op = ckr + kvh2 * 512 + c * 64 + d2;
            *(float4*)(op)     = make_float4(t[0], t[1], t[2], t[3]);
            *(float4*)(op + 4) = make_float4(t[4], t[5], t[6], t[7]);
        }
        return;
    }

    int m0 = blockIdx.y * 64;
    int n0g = (ntile < 16) ? ntile * 64 : 1024 + (ntile - 16) * 64;

    int lane = tid & 63, wave = tid >> 6;
    int r16 = lane & 15, quad = lane >> 4;
    int mb = (wave >> 1) * 32, nb = (wave & 1) * 32;
    int srow = tid >> 3;
    int skg = (((tid & 7) ^ (srow & 7)) << 3);

#define STAGE_QKV(buf, k0)                                                         \
    do {                                                                           \
        GLL16(Ab + (size_t)(m0 + srow) * 1024 + (k0) + skg,       As[buf] + tid * 8);        \
        GLL16(Ab + (size_t)(m0 + srow + 32) * 1024 + (k0) + skg,  As[buf] + (tid + 256) * 8);\
        GLL16(BT + (size_t)(n0g + srow) * 1024 + (k0) + skg,      Bs[buf] + tid * 8);        \
        GLL16(BT + (size_t)(n0g + srow + 32) * 1024 + (k0) + skg, Bs[buf] + (tid + 256) * 8);\
    } while (0)

    f32x4 acc[2][2];
#pragma unroll
    for (int mt = 0; mt < 2; mt++)
#pragma unroll
        for (int nt = 0; nt < 2; nt++) acc[mt][nt] = (f32x4){0.f, 0.f, 0.f, 0.f};

    STAGE_QKV(0, 0);
    __syncthreads();
    int cur = 0;
    for (int k0 = 0; k0 < 1024; k0 += 64) {
        if (k0 + 64 < 1024) STAGE_QKV(cur ^ 1, k0 + 64);
#pragma unroll
        for (int ks = 0; ks < 2; ks++) {
            bf16x8 af[2], bfr[2];
#pragma unroll
            for (int mt = 0; mt < 2; mt++) {
                int r = mb + mt * 16 + r16;
                af[mt] = *(const bf16x8*)(As[cur] + r * 64 +
                                          ((ks * 32 + quad * 8) ^ ((r & 7) << 3)));
            }
#pragma unroll
            for (int nt = 0; nt < 2; nt++) {
                int r = nb + nt * 16 + r16;
                bfr[nt] = *(const bf16x8*)(Bs[cur] + r * 64 +
                                           ((ks * 32 + quad * 8) ^ ((r & 7) << 3)));
            }
#pragma unroll
            for (int mt = 0; mt < 2; mt++)
#pragma unroll
                for (int nt = 0; nt < 2; nt++)
                    acc[mt][nt] = __builtin_amdgcn_mfma_f32_16x16x32_bf16(af[mt], bfr[nt], acc[mt][nt], 0, 0, 0);
        }
        __syncthreads();
        cur ^= 1;
    }
    if (ntile < 20) {
        u16* Cout; int BN, n0;
        if (ntile < 16) { Cout = qout;  BN = 1024; n0 = ntile * 64; }
        else            { Cout = kvout; BN = 512;  n0 = (ntile - 16) * 64; }
#pragma unroll
        for (int mt = 0; mt < 2; mt++)
#pragma unroll
            for (int nt = 0; nt < 2; nt++)
#pragma unroll
                for (int rg = 0; rg < 4; rg++) {
                    int row = m0 + mb + mt * 16 + quad * 4 + rg;
                    int col = n0 + nb + nt * 16 + r16;
                    Cout[(size_t)row * BN + col] = f2b(acc[mt][nt][rg]);
                }
    } else {
        // V-half: transposed store vt[b][kvh*64+d][s]; col in [256,512)
        int n0 = (ntile - 16) * 64;
#pragma unroll
        for (int mt = 0; mt < 2; mt++)
#pragma unroll
            for (int nt = 0; nt < 2; nt++)
#pragma unroll
                for (int rg = 0; rg < 4; rg++) {
                    int row = m0 + mb + mt * 16 + quad * 4 + rg;
                    int col = n0 + nb + nt * 16 + r16;  // in [256,512)
                    int bb = row >> 10, s = row & 1023;
                    vtb[((size_t)bb << 18) + ((size_t)(col - 256) << 10) + s] =
                        f2b(acc[mt][nt][rg]);
                }
    }
#undef STAGE_QKV
}

// ---------------------------------------------------------------------------
// mgemm_proj3: 64x64-tile output projection, BK=64 + XOR-swizzled LDS.
// Round-12: k_merge FUSED. Each m-tile covers exactly one g (64-aligned);
// each K-step covers exactly one head h = k0>>6 -> for g>=8 tiles the A
// operand is computed inline from the two split-KV partials (pacc/pml),
// bit-identical math to the old k_merge, reg-staged into the same swizzled
// LDS layout. A2 merged rows are never materialized.
// ---------------------------------------------------------------------------
__global__ __launch_bounds__(256) void mgemm_proj3(const u16* __restrict__ Ab,
                                                   const u16* __restrict__ BT,
                                                   const float* __restrict__ pacc,
                                                   const float* __restrict__ pml,
                                                   float* __restrict__ Cf) {
    __shared__ __align__(16) u16 As[2][64 * 64];
    __shared__ __align__(16) u16 Bs[2][64 * 64];
    int tid = threadIdx.x;
    int n0 = blockIdx.x * 64;
    int m0 = blockIdx.y * 64;
    int bb = m0 >> 10, gg = (m0 & 1023) >> 6;
    bool merged = gg >= 8;
    int slotbase = bb * 256 + (gg - 8) * 2;  // + h*16 per K-step

    int lane = tid & 63, wave = tid >> 6;
    int r16 = lane & 15, quad = lane >> 4;
    int mb = (wave >> 1) * 32, nb = (wave & 1) * 32;
    int srow = tid >> 3;
    int skg = (((tid & 7) ^ (srow & 7)) << 3);

#define STAGE_B(buf, k0)                                                           \
    do {                                                                           \
        GLL16(BT + (size_t)(n0 + srow) * 1024 + (k0) + skg,      Bs[buf] + tid * 8);        \
        GLL16(BT + (size_t)(n0 + srow + 32) * 1024 + (k0) + skg, Bs[buf] + (tid + 256) * 8);\
    } while (0)

#define STAGE_A_DIRECT(buf, k0)                                                    \
    do {                                                                           \
        GLL16(Ab + (size_t)(m0 + srow) * 1024 + (k0) + skg,      As[buf] + tid * 8);        \
        GLL16(Ab + (size_t)(m0 + srow + 32) * 1024 + (k0) + skg, As[buf] + (tid + 256) * 8);\
    } while (0)

#define STAGE_A_MERGED(buf, k0)                                                    \
    do {                                                                           \
        int slot_ = slotbase + ((k0) >> 6) * 16;                                   \
        const float* a0_ = pacc + (size_t)slot_ * 4096;                            \
        const float* mlp_ = pml + slot_ * 128;                                     \
        _Pragma("unroll")                                                          \
        for (int rr = 0; rr < 2; rr++) {                                           \
            int r_ = srow + rr * 32;                                               \
            float m0v = mlp_[r_],       l0v = mlp_[64 + r_];                       \
            float m1v = mlp_[128 + r_], l1v = mlp_[192 + r_];                      \
            float M_ = fmaxf(m0v, m1v);                                            \
            float e0_ = __expf(m0v - M_), e1_ = __expf(m1v - M_);                  \
            float inv_ = 1.f / (l0v * e0_ + l1v * e1_);                            \
            const float* p0_ = a0_ + r_ * 64 + skg;                                \
            const float* p1_ = p0_ + 4096;                                         \
            float4 x0 = *(const float4*)(p0_);                                     \
            float4 x1 = *(const float4*)(p0_ + 4);                                 \
            float4 y0 = *(const float4*)(p1_);                                     \
            float4 y1 = *(const float4*)(p1_ + 4);                                 \
            u16 o_[8] = {f2b((x0.x * e0_ + y0.x * e1_) * inv_),                    \
                         f2b((x0.y * e0_ + y0.y * e1_) * inv_),                    \
                         f2b((x0.z * e0_ + y0.z * e1_) * inv_),                    \
                         f2b((x0.w * e0_ + y0.w * e1_) * inv_),                    \
                         f2b((x1.x * e0_ + y1.x * e1_) * inv_),                    \
                         f2b((x1.y * e0_ + y1.y * e1_) * inv_),                    \
                         f2b((x1.z * e0_ + y1.z * e1_) * inv_),                    \
                         f2b((x1.w * e0_ + y1.w * e1_) * inv_)};                   \
            *(uint4*)(As[buf] + (tid + rr * 256) * 8) = *(uint4*)o_;               \
        }                                                                          \
    } while (0)

    f32x4 acc[2][2];
#pragma unroll
    for (int mt = 0; mt < 2; mt++)
#pragma unroll
        for (int nt = 0; nt < 2; nt++) acc[mt][nt] = (f32x4){0.f, 0.f, 0.f, 0.f};

    STAGE_B(0, 0);
    if (merged) STAGE_A_MERGED(0, 0); else STAGE_A_DIRECT(0, 0);
    __syncthreads();
    int cur = 0;
    for (int k0 = 0; k0 < 1024; k0 += 64) {
        if (k0 + 64 < 1024) {
            STAGE_B(cur ^ 1, k0 + 64);
            if (merged) STAGE_A_MERGED(cur ^ 1, k0 + 64);
            else STAGE_A_DIRECT(cur ^ 1, k0 + 64);
        }
#pragma unroll
        for (int ks = 0; ks < 2; ks++) {
            bf16x8 af[2], bfr[2];
#pragma unroll
            for (int mt = 0; mt < 2; mt++) {
                int r = mb + mt * 16 + r16;
                af[mt] = *(const bf16x8*)(As[cur] + r * 64 +
                                          ((ks * 32 + quad * 8) ^ ((r & 7) << 3)));
            }
#pragma unroll
            for (int nt = 0; nt < 2; nt++) {
                int r = nb + nt * 16 + r16;
                bfr[nt] = *(const bf16x8*)(Bs[cur] + r * 64 +
                                           ((ks * 32 + quad * 8) ^ ((r & 7) << 3)));
            }
#pragma unroll
            for (int mt = 0; mt < 2; mt++)
#pragma unroll
                for (int nt = 0; nt < 2; nt++)
                    acc[mt][nt] = __builtin_amdgcn_mfma_f32_16x16x32_bf16(af[mt], bfr[nt], acc[mt][nt], 0, 0, 0);
        }
        __syncthreads();
        cur ^= 1;
    }
#pragma unroll
    for (int mt = 0; mt < 2; mt++)
#pragma unroll
        for (int nt = 0; nt < 2; nt++)
#pragma unroll
            for (int rg = 0; rg < 4; rg++) {
                int row = m0 + mb + mt * 16 + quad * 4 + rg;
                int col = n0 + nb + nt * 16 + r16;
                Cf[(size_t)row * 1024 + col] = acc[mt][nt][rg];
            }
#undef STAGE_B
#undef STAGE_A_DIRECT
#undef STAGE_A_MERGED
}

// ---------------------------------------------------------------------------
// k_att4: flash attention, chunk=64, split-KV for g>=8.
// Round-12: (1) T13 defer-max (THR=8): skip max-update/rescale when chunk max
// doesn't grow past m+8 (m/l/accv stay mutually consistent -> merge exact);
// (2) prologue ta MFMA band-skip: only compute bands whose x range intersects
// the spi rows this mode actually reads ([8*clo, 8*chi)).
// ---------------------------------------------------------------------------
__global__ __launch_bounds__(256, 3) void k_att4(const u16* __restrict__ qb,
                                                 const u16* __restrict__ kvb,
                                                 const u16* __restrict__ vt,
                                                 const u16* __restrict__ tkr,
                                                 const float* __restrict__ ckr,
                                                 const float* __restrict__ bias,
                                                 u16* __restrict__ A2,
                                                 float* __restrict__ pacc,
                                                 float* __restrict__ pml) {
    __shared__ __align__(16) char smem[49664];
    u16*   taX  = (u16*)(smem);              // [128 spi][68 row] bf16, pre-shifted ta
    u16*   qg   = (u16*)(smem);              // [64][72] bf16 (q + gb), prologue alias
    u16*   tkS  = (u16*)(smem + 17408);      // prologue: tk [128][72] bf16
    u16*   Kst  = (u16*)(smem + 17408);      // loop: K chunk [64][72] bf16
    u16*   Vst  = (u16*)(smem + 26624);      // loop: V chunk [64][72] bf16 (d-major)
    u16*   Pst  = (u16*)(smem + 35840);      // P [64][72] bf16 (wave-private rows)
    float* csA  = (float*)(smem + 45056);    // [64][8] chan scores
    float* cks  = (float*)(smem + 47104);    // [8][64] ck rows
    float* cbmg = (float*)(smem + 49152);    // [64] cb - gb
    float* tbv  = (float*)(smem + 49408);    // [64] tb

    // x -> (g, mode): mode 2 = full, 0 = half0, 1 = half1.
    // Layout chosen so CU triples {x, x+8, x+16} each total 17 chunk-64s.
    static const unsigned char Gt[24] = {15,15,14,14,13,13,12,12,
                                          7, 6,11,11,10,10, 9, 5,
                                          0, 1, 2, 8, 3, 9, 8, 4};
    static const unsigned char Mt[24] = {0,1,1,0,0,1,1,0,
                                         2,2,0,1,1,0,0,2,
                                         2,2,2,0,2,1,1,2};

    int tid = threadIdx.x;
    int lane = tid & 63, wave = tid >> 6;
    int r16 = lane & 15, quad = lane >> 4;
    int h = blockIdx.y, b = blockIdx.z;
    int g = Gt[blockIdx.x], mode = Mt[blockIdx.x];
    int kvh = h >> 2;
    int t0 = g * 64;
    int hn = (g + 1) >> 1;
    int clo = (mode == 1) ? hn : 0;
    int chi = (mode == 0) ? hn : (g + 1);

    // per-thread staging bases (16 u16 per thread per chunk for V and K)
    const u16* vptr = vt + ((size_t)(b * KVHH + kvh)) * DD * TT
                    + (size_t)(tid >> 3) * TT + ((tid & 7) << 3);
    const u16* kptr = kvb + ((size_t)(b * TT) + (tid >> 3)) * (2 * EKVV)
                    + kvh * 64 + ((tid & 7) << 3);

    uint4 V0g, V1g, K0g, K1g;
    bool pk_next;

#define PRE(c0p)                                                               \
    do {                                                                       \
        V0g = *(const uint4*)(vptr + (c0p));                                   \
        V1g = *(const uint4*)(vptr + 32 * TT + (c0p));                         \
        pk_next = (g == 15) || ((c0p) + 136 > g * 64);                         \
        if (pk_next) {                                                         \
            const u16* kp_ = kptr + (size_t)(c0p) * (2 * EKVV);                \
            K0g = *(const uint4*)(kp_);                                        \
            K1g = *(const uint4*)(kp_ + 32 * 2 * EKVV);                        \
        }                                                                      \
    } while (0)

    PRE(clo * 64);  // first chunk's loads fly during the whole prologue

    // ---- prologue staging: qg (q+gb), cks, cbmg, tbv ----
#pragma unroll
    for (int i = 0; i < 2; i++) {
        int idx = tid + i * 256;
        int row = idx >> 3, dg = (idx & 7) << 3;
        uint4 u = *(const uint4*)(qb + ((size_t)(b * TT + t0 + row)) * EE + h * 64 + dg);
        u16 tmp[8]; *(uint4*)tmp = u;
        u16 o[8];
#pragma unroll
        for (int j = 0; j < 8; j++) o[j] = f2b(b2f(tmp[j]) + bias[kvh * 64 + dg + j]);
        *(uint4*)(qg + row * 72 + dg) = *(uint4*)o;
    }
    if (tid < 64) {
        cbmg[tid] = bias[2 * EKVV + kvh * 64 + tid] - bias[kvh * 64 + tid];
        tbv[tid]  = bias[EKVV + kvh * 64 + tid];
    }
#pragma unroll
    for (int i = 0; i < 2; i++) {
        int idx = tid + i * 256;
        cks[idx] = ckr[kvh * 512 + idx];
    }
    __syncthreads();  // B1

    // ---- channel scores ----
    {
        int row = tid >> 2, cA = (tid & 3) << 1;
        int rm8 = row & 7;
        int d0 = rm8 - cA;       if (d0 < 0) d0 = -d0;
        int d1 = rm8 - (cA + 1); if (d1 < 0) d1 = -d1;
        const float* k0p = cks + (7 - d0) * 64;
        const float* k1p = cks + (7 - d1) * 64;
        float a0 = 0.f, a1 = 0.f;
#pragma unroll 8
        for (int d = 0; d < 64; d++) {
            float qv = b2f(qg[row * 72 + d]) + cbmg[d];
            a0 += qv * k0p[d];
            a1 += qv * k1p[d];
        }
        csA[row * 8 + cA] = a0;
        csA[row * 8 + cA + 1] = a1;
    }

    // ---- q fragments: q+gb (from qg) and q+tb (fresh from qb + tbv) ----
    bf16x8 aq0 = *(const bf16x8*)(qg + (wave * 16 + r16) * 72 + quad * 8);
    bf16x8 aq1 = *(const bf16x8*)(qg + (wave * 16 + r16) * 72 + 32 + quad * 8);
    bf16x8 aqt0, aqt1;
    {
        const u16* qrow = qb + ((size_t)(b * TT + t0 + wave * 16 + r16)) * EE + h * 64;
        uint4 u0 = *(const uint4*)(qrow + quad * 8);
        uint4 u1 = *(const uint4*)(qrow + 32 + quad * 8);
        u16 t0v[8], t1v[8]; *(uint4*)t0v = u0; *(uint4*)t1v = u1;
        u16 o0[8], o1[8];
#pragma unroll
        for (int j = 0; j < 8; j++) {
            o0[j] = f2b(b2f(t0v[j]) + tbv[quad * 8 + j]);
            o1[j] = f2b(b2f(t1v[j]) + tbv[32 + quad * 8 + j]);
        }
        aqt0 = *(bf16x8*)o0;
        aqt1 = *(bf16x8*)o1;
    }

    // ---- stage tk -> tkS (bf16 [128][72]) from pre-reduced tkr ----
    {
        const u16* tkp = tkr + kvh * 8192;
#pragma unroll
        for (int i = 0; i < 4; i++) {
            int idx = tid + i * 256;
            int p = idx >> 3, dg = (idx & 7) << 3;
            *(uint4*)(tkS + p * 72 + dg) = *(const uint4*)(tkp + p * 64 + dg);
        }
    }
    __syncthreads();  // B2: qg reads done; tk visible

    // ---- ta = (q+tb) * tk^T, rel-shifted at write; band-skip outside the
    //      spi rows this mode reads ([8*clo, 8*chi)) ----
    int rpi_w = (t0 >> 3) + wave * 2 + (quad >> 1);  // rpi, same for all 4 rg rows
    int xsh = rpi_w - 127;
    int xshw = (t0 >> 3) + wave * 2 - 127;  // wave-uniform lower bound of xsh
    int blo = 8 * clo, bhi = 8 * chi;
#pragma unroll
    for (int nt = 0; nt < 8; nt++) {
        int bl = nt * 16 + xshw;           // band covers x in [bl, bl+17)
        if (bl + 17 <= blo || bl >= bhi) continue;
        const u16* kp = tkS + (nt * 16 + r16) * 72 + quad * 8;
        bf16x8 b0 = *(const bf16x8*)(kp);
        bf16x8 b1 = *(const bf16x8*)(kp + 32);
        f32x4 a = {0.f, 0.f, 0.f, 0.f};
        a = __builtin_amdgcn_mfma_f32_16x16x32_bf16(aqt0, b0, a, 0, 0, 0);
        a = __builtin_amdgcn_mfma_f32_16x16x32_bf16(aqt1, b1, a, 0, 0, 0);
        int x = nt * 16 + r16 + xsh;
        if (x >= 0) {
            u16 o4[4] = {f2b(a[0]), f2b(a[1]), f2b(a[2]), f2b(a[3])};
            *(ushort4*)(taX + x * 68 + wave * 16 + quad * 4) = *(ushort4*)o4;
        }
    }

    float m[4], l[4];
    f32x4 accv[4];
#pragma unroll
    for (int rg = 0; rg < 4; rg++) { m[rg] = -1.0e30f; l[rg] = 0.f; }
#pragma unroll
    for (int nt = 0; nt < 4; nt++) accv[nt] = (f32x4){0.f, 0.f, 0.f, 0.f};

    int rowbase = wave * 16 + quad * 4;
    int rpi[4];
#pragma unroll
    for (int rg = 0; rg < 4; rg++) rpi[rg] = (t0 + rowbase + rg) >> 3;

    for (int ci = clo; ci < chi; ci++) {
        int c0 = ci * 64;
        bool pk = pk_next;
        __syncthreads();  // S1: all waves done with prev chunk LDS + prologue tkS reads
        {
            u16* vw = Vst + (tid >> 3) * 72 + ((tid & 7) << 3);
            *(uint4*)(vw)           = V0g;
            *(uint4*)(vw + 32 * 72) = V1g;
            if (pk) {
                u16* kw = Kst + (tid >> 3) * 72 + ((tid & 7) << 3);
                *(uint4*)(kw)           = K0g;
                *(uint4*)(kw + 32 * 72) = K1g;
            }
        }
        if (ci + 1 < chi) PRE((ci + 1) * 64);  // next chunk flies under compute
        __syncthreads();  // S2: staged data visible

        // per-wave QK gating (superset of the win mask; exact, no off-by-one
        // since 64 never divides 64g+16w-136)
        bool pkq = (c0 + 136 - 16 * wave > g * 64) || (g == 15 && wave == 3);
        f32x4 sc[4];
        if (pkq) {
            __builtin_amdgcn_s_setprio(1);
#pragma unroll
            for (int nt = 0; nt < 4; nt++) {
                const u16* kp = Kst + (nt * 16 + r16) * 72 + quad * 8;
                bf16x8 b0 = *(const bf16x8*)(kp);
                bf16x8 b1 = *(const bf16x8*)(kp + 32);
                f32x4 a = {0.f, 0.f, 0.f, 0.f};
                a = __builtin_amdgcn_mfma_f32_16x16x32_bf16(aq0, b0, a, 0, 0, 0);
                a = __builtin_amdgcn_mfma_f32_16x16x32_bf16(aq1, b1, a, 0, 0, 0);
                sc[nt] = a;
            }
            __builtin_amdgcn_s_setprio(0);
        } else {
#pragma unroll
            for (int nt = 0; nt < 4; nt++) sc[nt] = (f32x4){0.f, 0.f, 0.f, 0.f};
        }

        float csr[4];
#pragma unroll
        for (int rg = 0; rg < 4; rg++) csr[rg] = csA[(rowbase + rg) * 8 + (r16 & 7)];
        int c08 = c0 >> 3;
#pragma unroll
        for (int nt = 0; nt < 4; nt++) {
            int spi = c08 + 2 * nt + (r16 >> 3);
            // pre-shifted ta: one b64 read serves all 4 rows of this thread.
            // spi > rpi reads unwritten bytes (in-bounds) -> masked below.
            ushort4 t4 = *(const ushort4*)(taX + spi * 68 + rowbase);
            float tsv[4] = {b2f(t4.x), b2f(t4.y), b2f(t4.z), b2f(t4.w)};
#pragma unroll
            for (int rg = 0; rg < 4; rg++) {
                bool win = (rpi[rg] == 127) || (rpi[rg] - spi <= 10);
                float scv = ((win ? sc[nt][rg] : 0.f) + tsv[rg] + csr[rg]) * 0.125f;
                sc[nt][rg] = (spi <= rpi[rg]) ? scv : -1.0e30f;
            }
        }

        // ---- online softmax with T13 defer-max (THR=8) ----
        float cm[4], alpha[4], psum[4];
        bool anyresc = false;
#pragma unroll
        for (int rg = 0; rg < 4; rg++) {
            float v = sc[0][rg];
#pragma unroll
            for (int nt = 1; nt < 4; nt++) v = fmaxf(v, sc[nt][rg]);
            v = red_max16(v);
            if (v > m[rg] + 8.f) {
                alpha[rg] = __expf(m[rg] - v);
                m[rg] = v;
                anyresc = true;
            } else {
                alpha[rg] = 1.f;
            }
            cm[rg] = m[rg];
        }
#pragma unroll
        for (int rg = 0; rg < 4; rg++) psum[rg] = 0.f;
#pragma unroll
        for (int nt = 0; nt < 4; nt++)
#pragma unroll
            for (int rg = 0; rg < 4; rg++) {
                float e = __expf(sc[nt][rg] - cm[rg]);
                sc[nt][rg] = e;
                psum[rg] += e;
            }
#pragma unroll
        for (int rg = 0; rg < 4; rg++) {
            psum[rg] = red_sum16(psum[rg]);
            l[rg] = l[rg] * alpha[rg] + psum[rg];
        }
        if (anyresc) {
#pragma unroll
            for (int nt = 0; nt < 4; nt++)
#pragma unroll
                for (int rg = 0; rg < 4; rg++) accv[nt][rg] *= alpha[rg];
        }

        // P store: wave-private rows -> no barrier needed around it
#pragma unroll
        for (int nt = 0; nt < 4; nt++)
#pragma unroll
            for (int rg = 0; rg < 4; rg++)
                Pst[(rowbase + rg) * 72 + nt * 16 + r16] = f2b(sc[nt][rg]);

        __builtin_amdgcn_s_setprio(1);
#pragma unroll
        for (int ks = 0; ks < 2; ks++) {
            bf16x8 ap = *(const bf16x8*)(Pst + (wave * 16 + r16) * 72 + ks * 32 + quad * 8);
#pragma unroll
            for (int nt = 0; nt < 4; nt++) {
                bf16x8 bv = *(const bf16x8*)(Vst + (nt * 16 + r16) * 72 + ks * 32 + quad * 8);
                accv[nt] = __builtin_amdgcn_mfma_f32_16x16x32_bf16(ap, bv, accv[nt], 0, 0, 0);
            }
        }
        __builtin_amdgcn_s_setprio(0);
    }
#undef PRE

    if (mode == 2) {
#pragma unroll
        for (int nt = 0; nt < 4; nt++)
#pragma unroll
            for (int rg = 0; rg < 4; rg++) {
                int rt = t0 + rowbase + rg;
                A2[((size_t)(b * TT + rt)) * EE + h * 64 + nt * 16 + r16] =
                    f2b(accv[nt][rg] / l[rg]);
            }
    } else {
        int slot = ((b * 16 + h) * 8 + (g - 8)) * 2 + mode;
        float* pa = pacc + (size_t)slot * 4096;
#pragma unroll
        for (int nt = 0; nt < 4; nt++)
#pragma unroll
            for (int rg = 0; rg < 4; rg++)
                pa[(rowbase + rg) * 64 + nt * 16 + r16] = accv[nt][rg];
        if (r16 == 0) {
#pragma unroll
            for (int rg = 0; rg < 4; rg++) {
                pml[slot * 128 + rowbase + rg]      = m[rg];
                pml[slot * 128 + 64 + rowbase + rg] = l[rg];
            }
        }
    }
}

extern "C" void kernel_launch(void* const* d_in, const int* in_sizes, int n_in,
                              void* d_out, int out_size, void* d_ws, size_t ws_size,
                              hipStream_t stream) {
    const float* hidden = (const float*)d_in[0];
    const float* pos    = (const float*)d_in[1];
    const float* chan   = (const float*)d_in[2];
    const float* Wq     = (const float*)d_in[3];
    const float* Wkv    = (const float*)d_in[4];
    const float* Wpos   = (const float*)d_in[5];
    const float* Wchan  = (const float*)d_in[6];
    const float* Wproj  = (const float*)d_in[7];
    const float* bias   = (const float*)d_in[8];

    // workspace carve: ~31.5 MB total
    u16* qb    = (u16*)d_ws;               // 2,097,152 u16 (4 MB)
    u16* kvb   = qb + 2097152;             // 1,048,576 u16 (2 MB)
    u16* A2    = kvb + 1048576;            // 2,097,152 u16 (4 MB)
    u16* vt    = A2 + 2097152;             //   524,288 u16 (1 MB)
    u16* hb    = vt + 524288;              // 2,097,152 u16 (4 MB) hidden bf16
    u16* btq   = hb + 2097152;             // 1,572,864 u16 (3 MB) [Wq;Wkv]^T bf16
    u16* btp   = btq + 1572864;            // 1,048,576 u16 (2 MB) Wproj^T bf16
    u16* tkr   = btp + 1048576;            //    32,768 u16 (64 KB) reduced tk bf16
    float* tkb = (float*)(tkr + 32768);    // 16 x 32,768 f32 (split-K slices)
    float* ckb = tkb + 524288;             // 16 x  2,048 f32 (split-K slices)
    float* ckr = ckb + 32768;              //     2,048 f32 (8 KB) reduced ck
    float* pacc = ckr + 2048;              // 512 x 4096 f32 (8 MB) partial acc
    float* pml  = pacc + 2097152;          // 512 x 128 f32 (256 KB) partial m/l

    dim3 blk(256);
    // one-time conversions + weight transposes + tiny projections (fused)
    k_prep<<<3776, blk, 0, stream>>>(hidden, Wq, Wkv, Wproj, pos, chan, Wpos, Wchan,
                                     hb, btq, btp, tkb, ckb);
    // fused q/kv projection via 64x64 MFMA tiles (BK=64, swizzled) + reductions
    mgemm_qkv3<<<dim3(25, 32), blk, 0, stream>>>(hb, btq, qb, kvb, vt,
                                                 tkb, ckb, tkr, ckr);
    // split-KV flash attention (chunk 64, 3 blocks/CU) -> A2 + partials
    k_att4<<<dim3(24, 16, 2), blk, 0, stream>>>(qb, kvb, vt, tkr, ckr, bias, A2,
                                                pacc, pml);
    // output projection via 64x64 MFMA tiles, split-KV merge fused in A-staging
    mgemm_proj3<<<dim3(16, 32), blk, 0, stream>>>(A2, btp, pacc, pml, (float*)d_out);
}

// Round 13
// 145.074 us; speedup vs baseline: 1.0434x; 1.0434x over previous
//
#include <hip/hip_runtime.h>
#include <hip/hip_bf16.h>

#define BB 2
#define PP 128
#define CC 8
#define EE 1024
#define HH 16
#define KVHH 4
#define DD 64
#define TT 1024
#define EKVV 256

typedef unsigned short u16;
typedef unsigned int u32;
typedef __attribute__((ext_vector_type(8))) short bf16x8;
typedef __attribute__((ext_vector_type(4))) float f32x4;

__device__ __forceinline__ float b2f(u16 u) {
    u32 x = ((u32)u) << 16;
    return __uint_as_float(x);
}
__device__ __forceinline__ u16 f2b(float f) {
    u32 x = __float_as_uint(f);
    u32 r = (x + 0x7FFFu + ((x >> 16) & 1u)) >> 16;
    return (u16)r;
}

// DPP 16-lane reductions (VALU-only; replaces ds_swizzle shfl chains).
template <int CTRL>
__device__ __forceinline__ float dpp_mv(float v) {
    return __int_as_float(__builtin_amdgcn_update_dpp(
        __float_as_int(v), __float_as_int(v), CTRL, 0xF, 0xF, true));
}
__device__ __forceinline__ float red_max16(float v) {
    v = fmaxf(v, dpp_mv<0xB1>(v));   // quad_perm xor1
    v = fmaxf(v, dpp_mv<0x4E>(v));   // quad_perm xor2
    v = fmaxf(v, dpp_mv<0x141>(v));  // row_half_mirror
    v = fmaxf(v, dpp_mv<0x140>(v));  // row_mirror
    return v;
}
__device__ __forceinline__ float red_sum16(float v) {
    v += dpp_mv<0xB1>(v);
    v += dpp_mv<0x4E>(v);
    v += dpp_mv<0x141>(v);
    v += dpp_mv<0x140>(v);
    return v;
}

// async global->LDS 16B (wave-uniform LDS base + lane*16 layout required)
#define GLL16(gp, lp)                                                          \
    __builtin_amdgcn_global_load_lds(                                          \
        (__attribute__((address_space(1))) void*)(gp),                         \
        (__attribute__((address_space(3))) void*)(lp), 16, 0, 0)

// ---------------------------------------------------------------------------
// k_prep: one-time conversions + the two tiny fp32 projections (fused).
//   blocks [0,192):     pos/chan projections, split-K=16 slices (K=64 each)
//   blocks [192,1216):  hidden f32 -> bf16 (hb)
//   blocks [1216,2240): Wq    -> btq rows [0,1024)    (transposed bf16)
//   blocks [2240,2752): Wkv   -> btq rows [1024,1536) (transposed bf16)
//   blocks [2752,3776): Wproj -> btp                  (transposed bf16)
// ---------------------------------------------------------------------------
__global__ __launch_bounds__(256) void k_prep(const float* __restrict__ hidden,
                                              const float* __restrict__ Wq,
                                              const float* __restrict__ Wkv,
                                              const float* __restrict__ Wproj,
                                              const float* __restrict__ pos,
                                              const float* __restrict__ chan,
                                              const float* __restrict__ Wpos,
                                              const float* __restrict__ Wchan,
                                              u16* __restrict__ hb,
                                              u16* __restrict__ btq,
                                              u16* __restrict__ btp,
                                              float* __restrict__ tkb,
                                              float* __restrict__ ckb) {
    __shared__ __align__(16) char sm[8704];
    int bid = blockIdx.x;
    int tid = threadIdx.x;

    if (bid < 192) {
        // tiny fp32 GEMM, K-slice (64) per block, direct store (no atomics)
        int tile = bid >> 4, kh = bid & 15;
        float (*As)[68] = (float (*)[68])sm;
        float (*Bs)[68] = (float (*)[68])(sm + 4352);
        const float* A; const float* B; float* C; int M, m0, n0;
        if (tile < 8) { A = pos;  B = Wpos;  C = tkb + kh * 32768; M = 128; m0 = (tile >> 2) * 64; n0 = (tile & 3) * 64; }
        else          { A = chan; B = Wchan; C = ckb + kh * 2048;  M = 8;   m0 = 0;               n0 = (tile - 8) * 64; }
        int tx = tid & 15, ty = tid >> 4;
        float acc[4][4];
#pragma unroll
        for (int r = 0; r < 4; r++)
#pragma unroll
            for (int c = 0; c < 4; c++) acc[r][c] = 0.f;
        int am = tid >> 2, ak = (tid & 3) << 2;
        int bk = tid >> 4, bn = (tid & 15) << 2;
        for (int k0 = kh * 64; k0 < kh * 64 + 64; k0 += 16) {
            int row = m0 + am;
            float4 av;
            if (row < M) av = *reinterpret_cast<const float4*>(A + (size_t)row * 1024 + k0 + ak);
            else av = make_float4(0.f, 0.f, 0.f, 0.f);
            As[ak + 0][am] = av.x;
            As[ak + 1][am] = av.y;
            As[ak + 2][am] = av.z;
            As[ak + 3][am] = av.w;
            float4 bv = *reinterpret_cast<const float4*>(B + (size_t)(k0 + bk) * 256 + n0 + bn);
            Bs[bk][bn + 0] = bv.x;
            Bs[bk][bn + 1] = bv.y;
            Bs[bk][bn + 2] = bv.z;
            Bs[bk][bn + 3] = bv.w;
            __syncthreads();
#pragma unroll
            for (int kk = 0; kk < 16; kk++) {
                float4 a4 = *reinterpret_cast<const float4*>(&As[kk][ty << 2]);
                float4 b4 = *reinterpret_cast<const float4*>(&Bs[kk][tx << 2]);
                acc[0][0] += a4.x * b4.x; acc[0][1] += a4.x * b4.y; acc[0][2] += a4.x * b4.z; acc[0][3] += a4.x * b4.w;
                acc[1][0] += a4.y * b4.x; acc[1][1] += a4.y * b4.y; acc[1][2] += a4.y * b4.z; acc[1][3] += a4.y * b4.w;
                acc[2][0] += a4.z * b4.x; acc[2][1] += a4.z * b4.y; acc[2][2] += a4.z * b4.z; acc[2][3] += a4.z * b4.w;
                acc[3][0] += a4.w * b4.x; acc[3][1] += a4.w * b4.y; acc[3][2] += a4.w * b4.z; acc[3][3] += a4.w * b4.w;
            }
            __syncthreads();
        }
#pragma unroll
        for (int r = 0; r < 4; r++) {
            int row = m0 + (ty << 2) + r;
            if (row < M) {
#pragma unroll
                for (int c = 0; c < 4; c++) {
                    int col = n0 + (tx << 2) + c;
                    C[(size_t)row * 256 + col] = acc[r][c];
                }
            }
        }
        return;
    }
    bid -= 192;
    if (bid < 1024) {
        int base = (bid * 256 + tid) * 8;
        float4 a0 = *(const float4*)(hidden + base);
        float4 a1 = *(const float4*)(hidden + base + 4);
        u16 o[8] = {f2b(a0.x), f2b(a0.y), f2b(a0.z), f2b(a0.w),
                    f2b(a1.x), f2b(a1.y), f2b(a1.z), f2b(a1.w)};
        *(uint4*)(hb + base) = *(uint4*)o;
        return;
    }
    bid -= 1024;
    const float* W;
    u16* out;
    int N, tk, tn;
    if (bid < 1024) {
        W = Wq; out = btq; N = 1024; tk = bid >> 5; tn = bid & 31;
    } else if (bid < 1536) {
        int b2 = bid - 1024;
        W = Wkv; out = btq + 1024 * 1024; N = 512; tk = b2 >> 4; tn = b2 & 15;
    } else {
        int b2 = bid - 1536;
        W = Wproj; out = btp; N = 1024; tk = b2 >> 5; tn = b2 & 31;
    }
    float (*ts)[33] = (float (*)[33])sm;
    int r = tid >> 3, c4 = (tid & 7) << 2;
    float4 v = *(const float4*)(W + (size_t)(tk * 32 + r) * N + tn * 32 + c4);
    ts[r][c4 + 0] = v.x;
    ts[r][c4 + 1] = v.y;
    ts[r][c4 + 2] = v.z;
    ts[r][c4 + 3] = v.w;
    __syncthreads();
    u16 o[4] = {f2b(ts[c4 + 0][r]), f2b(ts[c4 + 1][r]),
                f2b(ts[c4 + 2][r]), f2b(ts[c4 + 3][r])};
    *(ushort4*)(out + (size_t)(tn * 32 + r) * 1024 + tk * 32 + c4) = *(ushort4*)o;
}

// ---------------------------------------------------------------------------
// mgemm_qkv3: 64x64-tile bf16 GEMM, BK=64 dbuf, XOR-swizzled LDS (round 11).
// ---------------------------------------------------------------------------
__global__ __launch_bounds__(256) void mgemm_qkv3(const u16* __restrict__ Ab,
                                                  const u16* __restrict__ BT,
                                                  u16* __restrict__ qout,
                                                  u16* __restrict__ kvout,
                                                  u16* __restrict__ vtb,
                                                  const float* __restrict__ tkb,
                                                  const float* __restrict__ ckb,
                                                  u16* __restrict__ tkr,
                                                  float* __restrict__ ckr) {
    __shared__ __align__(16) u16 As[2][64 * 64];
    __shared__ __align__(16) u16 Bs[2][64 * 64];
    int tid = threadIdx.x;
    int ntile = blockIdx.x;

    if (ntile == 24) {
        int y = blockIdx.y;
        if (y >= 16) return;
        // tk reduction: rows [y*8, y*8+8), 256 units of 8 cols each
        int p = y * 8 + (tid >> 5), col = (tid & 31) << 3;
        float s0 = 0.f, s1 = 0.f, s2 = 0.f, s3 = 0.f,
              s4 = 0.f, s5 = 0.f, s6 = 0.f, s7 = 0.f;
#pragma unroll
        for (int sl = 0; sl < 16; sl++) {
            const float* tp = tkb + sl * 32768 + p * 256 + col;
            float4 a0 = *(const float4*)(tp);
            float4 a1 = *(const float4*)(tp + 4);
            s0 += a0.x; s1 += a0.y; s2 += a0.z; s3 += a0.w;
            s4 += a1.x; s5 += a1.y; s6 += a1.z; s7 += a1.w;
        }
        u16 o[8] = {f2b(s0), f2b(s1), f2b(s2), f2b(s3),
                    f2b(s4), f2b(s5), f2b(s6), f2b(s7)};
        int kvh = col >> 6, d = col & 63;
        *(uint4*)(tkr + kvh * 8192 + p * 64 + d) = *(uint4*)o;
        if (y == 0) {
            // ck reduction: 8 c-rows x 256 cols
            int c = tid >> 5, cc = (tid & 31) << 3;
            float t[8];
#pragma unroll
            for (int j = 0; j < 8; j++) t[j] = 0.f;
#pragma unroll
            for (int sl = 0; sl < 16; sl++) {
                const float* cp = ckb + sl * 2048 + c * 256 + cc;
                float4 a0 = *(const float4*)(cp);
                float4 a1 = *(const float4*)(cp + 4);
                t[0] += a0.x; t[1] += a0.y; t[2] += a0.z; t[3] += a0.w;
                t[4] += a1.x; t[5] += a1.y; t[6] += a1.z; t[7] += a1.w;
            }
            int kvh2 = cc >> 6, d2 = cc & 63;
            float* op = ckr + kvh2 * 512 + c * 64 + d2;
            *(float4*)(op)     = make_float4(t[0], t[1], t[2], t[3]);
            *(float4*)(op + 4) = make_float4(t[4], t[5], t[6], t[7]);
        }
        return;
    }

    int m0 = blockIdx.y * 64;
    int n0g = (ntile < 16) ? ntile * 64 : 1024 + (ntile - 16) * 64;

    int lane = tid & 63, wave = tid >> 6;
    int r16 = lane & 15, quad = lane >> 4;
    int mb = (wave >> 1) * 32, nb = (wave & 1) * 32;
    int srow = tid >> 3;
    int skg = (((tid & 7) ^ (srow & 7)) << 3);

#define STAGE_QKV(buf, k0)                                                         \
    do {                                                                           \
        GLL16(Ab + (size_t)(m0 + srow) * 1024 + (k0) + skg,       As[buf] + tid * 8);        \
        GLL16(Ab + (size_t)(m0 + srow + 32) * 1024 + (k0) + skg,  As[buf] + (tid + 256) * 8);\
        GLL16(BT + (size_t)(n0g + srow) * 1024 + (k0) + skg,      Bs[buf] + tid * 8);        \
        GLL16(BT + (size_t)(n0g + srow + 32) * 1024 + (k0) + skg, Bs[buf] + (tid + 256) * 8);\
    } while (0)

    f32x4 acc[2][2];
#pragma unroll
    for (int mt = 0; mt < 2; mt++)
#pragma unroll
        for (int nt = 0; nt < 2; nt++) acc[mt][nt] = (f32x4){0.f, 0.f, 0.f, 0.f};

    STAGE_QKV(0, 0);
    __syncthreads();
    int cur = 0;
    for (int k0 = 0; k0 < 1024; k0 += 64) {
        if (k0 + 64 < 1024) STAGE_QKV(cur ^ 1, k0 + 64);
#pragma unroll
        for (int ks = 0; ks < 2; ks++) {
            bf16x8 af[2], bfr[2];
#pragma unroll
            for (int mt = 0; mt < 2; mt++) {
                int r = mb + mt * 16 + r16;
                af[mt] = *(const bf16x8*)(As[cur] + r * 64 +
                                          ((ks * 32 + quad * 8) ^ ((r & 7) << 3)));
            }
#pragma unroll
            for (int nt = 0; nt < 2; nt++) {
                int r = nb + nt * 16 + r16;
                bfr[nt] = *(const bf16x8*)(Bs[cur] + r * 64 +
                                           ((ks * 32 + quad * 8) ^ ((r & 7) << 3)));
            }
#pragma unroll
            for (int mt = 0; mt < 2; mt++)
#pragma unroll
                for (int nt = 0; nt < 2; nt++)
                    acc[mt][nt] = __builtin_amdgcn_mfma_f32_16x16x32_bf16(af[mt], bfr[nt], acc[mt][nt], 0, 0, 0);
        }
        __syncthreads();
        cur ^= 1;
    }
    if (ntile < 20) {
        u16* Cout; int BN, n0;
        if (ntile < 16) { Cout = qout;  BN = 1024; n0 = ntile * 64; }
        else            { Cout = kvout; BN = 512;  n0 = (ntile - 16) * 64; }
#pragma unroll
        for (int mt = 0; mt < 2; mt++)
#pragma unroll
            for (int nt = 0; nt < 2; nt++)
#pragma unroll
                for (int rg = 0; rg < 4; rg++) {
                    int row = m0 + mb + mt * 16 + quad * 4 + rg;
                    int col = n0 + nb + nt * 16 + r16;
                    Cout[(size_t)row * BN + col] = f2b(acc[mt][nt][rg]);
                }
    } else {
        // V-half: transposed store vt[b][kvh*64+d][s]; col in [256,512)
        int n0 = (ntile - 16) * 64;
#pragma unroll
        for (int mt = 0; mt < 2; mt++)
#pragma unroll
            for (int nt = 0; nt < 2; nt++)
#pragma unroll
                for (int rg = 0; rg < 4; rg++) {
                    int row = m0 + mb + mt * 16 + quad * 4 + rg;
                    int col = n0 + nb + nt * 16 + r16;  // in [256,512)
                    int bb = row >> 10, s = row & 1023;
                    vtb[((size_t)bb << 18) + ((size_t)(col - 256) << 10) + s] =
                        f2b(acc[mt][nt][rg]);
                }
    }
#undef STAGE_QKV
}

// ---------------------------------------------------------------------------
// mgemm_proj3: 64x64-tile output projection, BK=64 + XOR-swizzled LDS
// (round 11 — plain GLL16 A-staging, no merge fusion).
// ---------------------------------------------------------------------------
__global__ __launch_bounds__(256) void mgemm_proj3(const u16* __restrict__ Ab,
                                                   const u16* __restrict__ BT,
                                                   float* __restrict__ Cf) {
    __shared__ __align__(16) u16 As[2][64 * 64];
    __shared__ __align__(16) u16 Bs[2][64 * 64];
    int tid = threadIdx.x;
    int n0 = blockIdx.x * 64;
    int m0 = blockIdx.y * 64;

    int lane = tid & 63, wave = tid >> 6;
    int r16 = lane & 15, quad = lane >> 4;
    int mb = (wave >> 1) * 32, nb = (wave & 1) * 32;
    int srow = tid >> 3;
    int skg = (((tid & 7) ^ (srow & 7)) << 3);

#define STAGE_PRJ(buf, k0)                                                         \
    do {                                                                           \
        GLL16(Ab + (size_t)(m0 + srow) * 1024 + (k0) + skg,      As[buf] + tid * 8);        \
        GLL16(Ab + (size_t)(m0 + srow + 32) * 1024 + (k0) + skg, As[buf] + (tid + 256) * 8);\
        GLL16(BT + (size_t)(n0 + srow) * 1024 + (k0) + skg,      Bs[buf] + tid * 8);        \
        GLL16(BT + (size_t)(n0 + srow + 32) * 1024 + (k0) + skg, Bs[buf] + (tid + 256) * 8);\
    } while (0)

    f32x4 acc[2][2];
#pragma unroll
    for (int mt = 0; mt < 2; mt++)
#pragma unroll
        for (int nt = 0; nt < 2; nt++) acc[mt][nt] = (f32x4){0.f, 0.f, 0.f, 0.f};

    STAGE_PRJ(0, 0);
    __syncthreads();
    int cur = 0;
    for (int k0 = 0; k0 < 1024; k0 += 64) {
        if (k0 + 64 < 1024) STAGE_PRJ(cur ^ 1, k0 + 64);
#pragma unroll
        for (int ks = 0; ks < 2; ks++) {
            bf16x8 af[2], bfr[2];
#pragma unroll
            for (int mt = 0; mt < 2; mt++) {
                int r = mb + mt * 16 + r16;
                af[mt] = *(const bf16x8*)(As[cur] + r * 64 +
                                          ((ks * 32 + quad * 8) ^ ((r & 7) << 3)));
            }
#pragma unroll
            for (int nt = 0; nt < 2; nt++) {
                int r = nb + nt * 16 + r16;
                bfr[nt] = *(const bf16x8*)(Bs[cur] + r * 64 +
                                           ((ks * 32 + quad * 8) ^ ((r & 7) << 3)));
            }
#pragma unroll
            for (int mt = 0; mt < 2; mt++)
#pragma unroll
                for (int nt = 0; nt < 2; nt++)
                    acc[mt][nt] = __builtin_amdgcn_mfma_f32_16x16x32_bf16(af[mt], bfr[nt], acc[mt][nt], 0, 0, 0);
        }
        __syncthreads();
        cur ^= 1;
    }
#pragma unroll
    for (int mt = 0; mt < 2; mt++)
#pragma unroll
        for (int nt = 0; nt < 2; nt++)
#pragma unroll
            for (int rg = 0; rg < 4; rg++) {
                int row = m0 + mb + mt * 16 + quad * 4 + rg;
                int col = n0 + nb + nt * 16 + r16;
                Cf[(size_t)row * 1024 + col] = acc[mt][nt][rg];
            }
#undef STAGE_PRJ
}

// ---------------------------------------------------------------------------
// k_att4: flash attention, chunk=64, split-KV for g>=8 (round-9 verified
// structure). Only addition vs round 11: prologue ta MFMA band-skip —
// compute only bands whose x range intersects the spi rows this mode reads
// ([8*clo, 8*chi)); wave-uniform predicate, pure work removal (verified
// correct in round 12's passing run).
// ---------------------------------------------------------------------------
__global__ __launch_bounds__(256, 3) void k_att4(const u16* __restrict__ qb,
                                                 const u16* __restrict__ kvb,
                                                 const u16* __restrict__ vt,
                                                 const u16* __restrict__ tkr,
                                                 const float* __restrict__ ckr,
                                                 const float* __restrict__ bias,
                                                 u16* __restrict__ A2,
                                                 float* __restrict__ pacc,
                                                 float* __restrict__ pml) {
    __shared__ __align__(16) char smem[49664];
    u16*   taX  = (u16*)(smem);              // [128 spi][68 row] bf16, pre-shifted ta
    u16*   qg   = (u16*)(smem);              // [64][72] bf16 (q + gb), prologue alias
    u16*   tkS  = (u16*)(smem + 17408);      // prologue: tk [128][72] bf16
    u16*   Kst  = (u16*)(smem + 17408);      // loop: K chunk [64][72] bf16
    u16*   Vst  = (u16*)(smem + 26624);      // loop: V chunk [64][72] bf16 (d-major)
    u16*   Pst  = (u16*)(smem + 35840);      // P [64][72] bf16 (wave-private rows)
    float* csA  = (float*)(smem + 45056);    // [64][8] chan scores
    float* cks  = (float*)(smem + 47104);    // [8][64] ck rows
    float* cbmg = (float*)(smem + 49152);    // [64] cb - gb
    float* tbv  = (float*)(smem + 49408);    // [64] tb

    // x -> (g, mode): mode 2 = full, 0 = half0, 1 = half1.
    // Layout chosen so CU triples {x, x+8, x+16} each total 17 chunk-64s.
    static const unsigned char Gt[24] = {15,15,14,14,13,13,12,12,
                                          7, 6,11,11,10,10, 9, 5,
                                          0, 1, 2, 8, 3, 9, 8, 4};
    static const unsigned char Mt[24] = {0,1,1,0,0,1,1,0,
                                         2,2,0,1,1,0,0,2,
                                         2,2,2,0,2,1,1,2};

    int tid = threadIdx.x;
    int lane = tid & 63, wave = tid >> 6;
    int r16 = lane & 15, quad = lane >> 4;
    int h = blockIdx.y, b = blockIdx.z;
    int g = Gt[blockIdx.x], mode = Mt[blockIdx.x];
    int kvh = h >> 2;
    int t0 = g * 64;
    int hn = (g + 1) >> 1;
    int clo = (mode == 1) ? hn : 0;
    int chi = (mode == 0) ? hn : (g + 1);

    // per-thread staging bases (16 u16 per thread per chunk for V and K)
    const u16* vptr = vt + ((size_t)(b * KVHH + kvh)) * DD * TT
                    + (size_t)(tid >> 3) * TT + ((tid & 7) << 3);
    const u16* kptr = kvb + ((size_t)(b * TT) + (tid >> 3)) * (2 * EKVV)
                    + kvh * 64 + ((tid & 7) << 3);

    uint4 V0g, V1g, K0g, K1g;
    bool pk_next;

#define PRE(c0p)                                                               \
    do {                                                                       \
        V0g = *(const uint4*)(vptr + (c0p));                                   \
        V1g = *(const uint4*)(vptr + 32 * TT + (c0p));                         \
        pk_next = (g == 15) || ((c0p) + 136 > g * 64);                         \
        if (pk_next) {                                                         \
            const u16* kp_ = kptr + (size_t)(c0p) * (2 * EKVV);                \
            K0g = *(const uint4*)(kp_);                                        \
            K1g = *(const uint4*)(kp_ + 32 * 2 * EKVV);                        \
        }                                                                      \
    } while (0)

    PRE(clo * 64);  // first chunk's loads fly during the whole prologue

    // ---- prologue staging: qg (q+gb), cks, cbmg, tbv ----
#pragma unroll
    for (int i = 0; i < 2; i++) {
        int idx = tid + i * 256;
        int row = idx >> 3, dg = (idx & 7) << 3;
        uint4 u = *(const uint4*)(qb + ((size_t)(b * TT + t0 + row)) * EE + h * 64 + dg);
        u16 tmp[8]; *(uint4*)tmp = u;
        u16 o[8];
#pragma unroll
        for (int j = 0; j < 8; j++) o[j] = f2b(b2f(tmp[j]) + bias[kvh * 64 + dg + j]);
        *(uint4*)(qg + row * 72 + dg) = *(uint4*)o;
    }
    if (tid < 64) {
        cbmg[tid] = bias[2 * EKVV + kvh * 64 + tid] - bias[kvh * 64 + tid];
        tbv[tid]  = bias[EKVV + kvh * 64 + tid];
    }
#pragma unroll
    for (int i = 0; i < 2; i++) {
        int idx = tid + i * 256;
        cks[idx] = ckr[kvh * 512 + idx];
    }
    __syncthreads();  // B1

    // ---- channel scores ----
    {
        int row = tid >> 2, cA = (tid & 3) << 1;
        int rm8 = row & 7;
        int d0 = rm8 - cA;       if (d0 < 0) d0 = -d0;
        int d1 = rm8 - (cA + 1); if (d1 < 0) d1 = -d1;
        const float* k0p = cks + (7 - d0) * 64;
        const float* k1p = cks + (7 - d1) * 64;
        float a0 = 0.f, a1 = 0.f;
#pragma unroll 8
        for (int d = 0; d < 64; d++) {
            float qv = b2f(qg[row * 72 + d]) + cbmg[d];
            a0 += qv * k0p[d];
            a1 += qv * k1p[d];
        }
        csA[row * 8 + cA] = a0;
        csA[row * 8 + cA + 1] = a1;
    }

    // ---- q fragments: q+gb (from qg) and q+tb (fresh from qb + tbv) ----
    bf16x8 aq0 = *(const bf16x8*)(qg + (wave * 16 + r16) * 72 + quad * 8);
    bf16x8 aq1 = *(const bf16x8*)(qg + (wave * 16 + r16) * 72 + 32 + quad * 8);
    bf16x8 aqt0, aqt1;
    {
        const u16* qrow = qb + ((size_t)(b * TT + t0 + wave * 16 + r16)) * EE + h * 64;
        uint4 u0 = *(const uint4*)(qrow + quad * 8);
        uint4 u1 = *(const uint4*)(qrow + 32 + quad * 8);
        u16 t0v[8], t1v[8]; *(uint4*)t0v = u0; *(uint4*)t1v = u1;
        u16 o0[8], o1[8];
#pragma unroll
        for (int j = 0; j < 8; j++) {
            o0[j] = f2b(b2f(t0v[j]) + tbv[quad * 8 + j]);
            o1[j] = f2b(b2f(t1v[j]) + tbv[32 + quad * 8 + j]);
        }
        aqt0 = *(bf16x8*)o0;
        aqt1 = *(bf16x8*)o1;
    }

    // ---- stage tk -> tkS (bf16 [128][72]) from pre-reduced tkr ----
    {
        const u16* tkp = tkr + kvh * 8192;
#pragma unroll
        for (int i = 0; i < 4; i++) {
            int idx = tid + i * 256;
            int p = idx >> 3, dg = (idx & 7) << 3;
            *(uint4*)(tkS + p * 72 + dg) = *(const uint4*)(tkp + p * 64 + dg);
        }
    }
    __syncthreads();  // B2: qg reads done; tk visible

    // ---- ta = (q+tb) * tk^T, rel-shifted at write; band-skip outside the
    //      spi rows this mode reads ([8*clo, 8*chi)) ----
    int rpi_w = (t0 >> 3) + wave * 2 + (quad >> 1);  // rpi, same for all 4 rg rows
    int xsh = rpi_w - 127;
    int xshw = (t0 >> 3) + wave * 2 - 127;  // wave-uniform lower bound of xsh
    int blo = 8 * clo, bhi = 8 * chi;
#pragma unroll
    for (int nt = 0; nt < 8; nt++) {
        int bl = nt * 16 + xshw;           // band covers x in [bl, bl+17)
        if (bl + 17 <= blo || bl >= bhi) continue;
        const u16* kp = tkS + (nt * 16 + r16) * 72 + quad * 8;
        bf16x8 b0 = *(const bf16x8*)(kp);
        bf16x8 b1 = *(const bf16x8*)(kp + 32);
        f32x4 a = {0.f, 0.f, 0.f, 0.f};
        a = __builtin_amdgcn_mfma_f32_16x16x32_bf16(aqt0, b0, a, 0, 0, 0);
        a = __builtin_amdgcn_mfma_f32_16x16x32_bf16(aqt1, b1, a, 0, 0, 0);
        int x = nt * 16 + r16 + xsh;
        if (x >= 0) {
            u16 o4[4] = {f2b(a[0]), f2b(a[1]), f2b(a[2]), f2b(a[3])};
            *(ushort4*)(taX + x * 68 + wave * 16 + quad * 4) = *(ushort4*)o4;
        }
    }

    float m[4], l[4];
    f32x4 accv[4];
#pragma unroll
    for (int rg = 0; rg < 4; rg++) { m[rg] = -1.0e30f; l[rg] = 0.f; }
#pragma unroll
    for (int nt = 0; nt < 4; nt++) accv[nt] = (f32x4){0.f, 0.f, 0.f, 0.f};

    int rowbase = wave * 16 + quad * 4;
    int rpi[4];
#pragma unroll
    for (int rg = 0; rg < 4; rg++) rpi[rg] = (t0 + rowbase + rg) >> 3;

    for (int ci = clo; ci < chi; ci++) {
        int c0 = ci * 64;
        bool pk = pk_next;
        __syncthreads();  // S1: all waves done with prev chunk LDS + prologue tkS reads
        {
            u16* vw = Vst + (tid >> 3) * 72 + ((tid & 7) << 3);
            *(uint4*)(vw)           = V0g;
            *(uint4*)(vw + 32 * 72) = V1g;
            if (pk) {
                u16* kw = Kst + (tid >> 3) * 72 + ((tid & 7) << 3);
                *(uint4*)(kw)           = K0g;
                *(uint4*)(kw + 32 * 72) = K1g;
            }
        }
        if (ci + 1 < chi) PRE((ci + 1) * 64);  // next chunk flies under compute
        __syncthreads();  // S2: staged data visible

        // per-wave QK gating (superset of the win mask; exact, no off-by-one
        // since 64 never divides 64g+16w-136)
        bool pkq = (c0 + 136 - 16 * wave > g * 64) || (g == 15 && wave == 3);
        f32x4 sc[4];
        if (pkq) {
            __builtin_amdgcn_s_setprio(1);
#pragma unroll
            for (int nt = 0; nt < 4; nt++) {
                const u16* kp = Kst + (nt * 16 + r16) * 72 + quad * 8;
                bf16x8 b0 = *(const bf16x8*)(kp);
                bf16x8 b1 = *(const bf16x8*)(kp + 32);
                f32x4 a = {0.f, 0.f, 0.f, 0.f};
                a = __builtin_amdgcn_mfma_f32_16x16x32_bf16(aq0, b0, a, 0, 0, 0);
                a = __builtin_amdgcn_mfma_f32_16x16x32_bf16(aq1, b1, a, 0, 0, 0);
                sc[nt] = a;
            }
            __builtin_amdgcn_s_setprio(0);
        } else {
#pragma unroll
            for (int nt = 0; nt < 4; nt++) sc[nt] = (f32x4){0.f, 0.f, 0.f, 0.f};
        }

        float csr[4];
#pragma unroll
        for (int rg = 0; rg < 4; rg++) csr[rg] = csA[(rowbase + rg) * 8 + (r16 & 7)];
        int c08 = c0 >> 3;
#pragma unroll
        for (int nt = 0; nt < 4; nt++) {
            int spi = c08 + 2 * nt + (r16 >> 3);
            // pre-shifted ta: one b64 read serves all 4 rows of this thread.
            // spi > rpi reads unwritten bytes (in-bounds) -> masked below.
            ushort4 t4 = *(const ushort4*)(taX + spi * 68 + rowbase);
            float tsv[4] = {b2f(t4.x), b2f(t4.y), b2f(t4.z), b2f(t4.w)};
#pragma unroll
            for (int rg = 0; rg < 4; rg++) {
                bool win = (rpi[rg] == 127) || (rpi[rg] - spi <= 10);
                float scv = ((win ? sc[nt][rg] : 0.f) + tsv[rg] + csr[rg]) * 0.125f;
                sc[nt][rg] = (spi <= rpi[rg]) ? scv : -1.0e30f;
            }
        }

        float cm[4], alpha[4], psum[4];
#pragma unroll
        for (int rg = 0; rg < 4; rg++) {
            float v = sc[0][rg];
#pragma unroll
            for (int nt = 1; nt < 4; nt++) v = fmaxf(v, sc[nt][rg]);
            v = red_max16(v);
            float mn = fmaxf(m[rg], v);
            alpha[rg] = __expf(m[rg] - mn);
            m[rg] = mn;
            cm[rg] = mn;
        }
#pragma unroll
        for (int rg = 0; rg < 4; rg++) psum[rg] = 0.f;
#pragma unroll
        for (int nt = 0; nt < 4; nt++)
#pragma unroll
            for (int rg = 0; rg < 4; rg++) {
                float e = __expf(sc[nt][rg] - cm[rg]);
                sc[nt][rg] = e;
                psum[rg] += e;
            }
#pragma unroll
        for (int rg = 0; rg < 4; rg++) {
            psum[rg] = red_sum16(psum[rg]);
            l[rg] = l[rg] * alpha[rg] + psum[rg];
        }
#pragma unroll
        for (int nt = 0; nt < 4; nt++)
#pragma unroll
            for (int rg = 0; rg < 4; rg++) accv[nt][rg] *= alpha[rg];

        // P store: wave-private rows -> no barrier needed around it
#pragma unroll
        for (int nt = 0; nt < 4; nt++)
#pragma unroll
            for (int rg = 0; rg < 4; rg++)
                Pst[(rowbase + rg) * 72 + nt * 16 + r16] = f2b(sc[nt][rg]);

        __builtin_amdgcn_s_setprio(1);
#pragma unroll
        for (int ks = 0; ks < 2; ks++) {
            bf16x8 ap = *(const bf16x8*)(Pst + (wave * 16 + r16) * 72 + ks * 32 + quad * 8);
#pragma unroll
            for (int nt = 0; nt < 4; nt++) {
                bf16x8 bv = *(const bf16x8*)(Vst + (nt * 16 + r16) * 72 + ks * 32 + quad * 8);
                accv[nt] = __builtin_amdgcn_mfma_f32_16x16x32_bf16(ap, bv, accv[nt], 0, 0, 0);
            }
        }
        __builtin_amdgcn_s_setprio(0);
    }
#undef PRE

    if (mode == 2) {
#pragma unroll
        for (int nt = 0; nt < 4; nt++)
#pragma unroll
            for (int rg = 0; rg < 4; rg++) {
                int rt = t0 + rowbase + rg;
                A2[((size_t)(b * TT + rt)) * EE + h * 64 + nt * 16 + r16] =
                    f2b(accv[nt][rg] / l[rg]);
            }
    } else {
        int slot = ((b * 16 + h) * 8 + (g - 8)) * 2 + mode;
        float* pa = pacc + (size_t)slot * 4096;
#pragma unroll
        for (int nt = 0; nt < 4; nt++)
#pragma unroll
            for (int rg = 0; rg < 4; rg++)
                pa[(rowbase + rg) * 64 + nt * 16 + r16] = accv[nt][rg];
        if (r16 == 0) {
#pragma unroll
            for (int rg = 0; rg < 4; rg++) {
                pml[slot * 128 + rowbase + rg]      = m[rg];
                pml[slot * 128 + 64 + rowbase + rg] = l[rg];
            }
        }
    }
}

// ---------------------------------------------------------------------------
// k_merge: combine the two chunk-half partials for g in [8,16) -> A2.
// Exact two-way online-softmax merge (unnormalized accumulators).
// ---------------------------------------------------------------------------
__global__ __launch_bounds__(256) void k_merge(const float* __restrict__ pacc,
                                               const float* __restrict__ pml,
                                               u16* __restrict__ A2) {
    int tid = threadIdx.x;
    int x = blockIdx.x, h = blockIdx.y, b = blockIdx.z;
    int g = 8 + x;
    int slot = ((b * 16 + h) * 8 + x) * 2;
    const float* a0 = pacc + (size_t)slot * 4096;
    const float* a1 = a0 + 4096;
    const float* ml0 = pml + slot * 128;
    const float* ml1 = ml0 + 128;
    int row = tid >> 2, seg = (tid & 3) << 4;
    float m0 = ml0[row], l0 = ml0[64 + row];
    float m1 = ml1[row], l1 = ml1[64 + row];
    float M = fmaxf(m0, m1);
    float e0 = __expf(m0 - M), e1 = __expf(m1 - M);
    float inv = 1.f / (l0 * e0 + l1 * e1);
    u16 o[16];
#pragma unroll
    for (int j0 = 0; j0 < 16; j0 += 4) {
        float4 v0 = *(const float4*)(a0 + row * 64 + seg + j0);
        float4 v1 = *(const float4*)(a1 + row * 64 + seg + j0);
        o[j0 + 0] = f2b((v0.x * e0 + v1.x * e1) * inv);
        o[j0 + 1] = f2b((v0.y * e0 + v1.y * e1) * inv);
        o[j0 + 2] = f2b((v0.z * e0 + v1.z * e1) * inv);
        o[j0 + 3] = f2b((v0.w * e0 + v1.w * e1) * inv);
    }
    int rt = g * 64 + row;
    u16* outp = A2 + ((size_t)(b * TT + rt)) * EE + h * 64 + seg;
    *(uint4*)(outp)     = *(uint4*)o;
    *(uint4*)(outp + 8) = *(uint4*)(o + 8);
}

extern "C" void kernel_launch(void* const* d_in, const int* in_sizes, int n_in,
                              void* d_out, int out_size, void* d_ws, size_t ws_size,
                              hipStream_t stream) {
    const float* hidden = (const float*)d_in[0];
    const float* pos    = (const float*)d_in[1];
    const float* chan   = (const float*)d_in[2];
    const float* Wq     = (const float*)d_in[3];
    const float* Wkv    = (const float*)d_in[4];
    const float* Wpos   = (const float*)d_in[5];
    const float* Wchan  = (const float*)d_in[6];
    const float* Wproj  = (const float*)d_in[7];
    const float* bias   = (const float*)d_in[8];

    // workspace carve: ~31.5 MB total
    u16* qb    = (u16*)d_ws;               // 2,097,152 u16 (4 MB)
    u16* kvb   = qb + 2097152;             // 1,048,576 u16 (2 MB)
    u16* A2    = kvb + 1048576;            // 2,097,152 u16 (4 MB)
    u16* vt    = A2 + 2097152;             //   524,288 u16 (1 MB)
    u16* hb    = vt + 524288;              // 2,097,152 u16 (4 MB) hidden bf16
    u16* btq   = hb + 2097152;             // 1,572,864 u16 (3 MB) [Wq;Wkv]^T bf16
    u16* btp   = btq + 1572864;            // 1,048,576 u16 (2 MB) Wproj^T bf16
    u16* tkr   = btp + 1048576;            //    32,768 u16 (64 KB) reduced tk bf16
    float* tkb = (float*)(tkr + 32768);    // 16 x 32,768 f32 (split-K slices)
    float* ckb = tkb + 524288;             // 16 x  2,048 f32 (split-K slices)
    float* ckr = ckb + 32768;              //     2,048 f32 (8 KB) reduced ck
    float* pacc = ckr + 2048;              // 512 x 4096 f32 (8 MB) partial acc
    float* pml  = pacc + 2097152;          // 512 x 128 f32 (256 KB) partial m/l

    dim3 blk(256);
    // one-time conversions + weight transposes + tiny projections (fused)
    k_prep<<<3776, blk, 0, stream>>>(hidden, Wq, Wkv, Wproj, pos, chan, Wpos, Wchan,
                                     hb, btq, btp, tkb, ckb);
    // fused q/kv projection via 64x64 MFMA tiles (BK=64, swizzled) + reductions
    mgemm_qkv3<<<dim3(25, 32), blk, 0, stream>>>(hb, btq, qb, kvb, vt,
                                                 tkb, ckb, tkr, ckr);
    // split-KV flash attention (chunk 64, 3 blocks/CU) -> A2 + partials
    k_att4<<<dim3(24, 16, 2), blk, 0, stream>>>(qb, kvb, vt, tkr, ckr, bias, A2,
                                                pacc, pml);
    // merge chunk-half partials for g >= 8 -> A2
    k_merge<<<dim3(8, 16, 2), blk, 0, stream>>>(pacc, pml, A2);
    // output projection via 64x64 MFMA tiles (BK=64, swizzled) -> fp32 d_out
    mgemm_proj3<<<dim3(16, 32), blk, 0, stream>>>(A2, btp, (float*)d_out);
}